// Round 12
// baseline (281.817 us; speedup 1.0000x reference)
//
#include <hip/hip_runtime.h>

typedef short bf16x8 __attribute__((ext_vector_type(8)));
typedef float f32x4 __attribute__((ext_vector_type(4)));
typedef unsigned short u16;

__device__ __forceinline__ u16 f2bf(float f) {
    unsigned u = __builtin_bit_cast(unsigned, f);
    return (u16)((u + 0x7fffu + ((u >> 16) & 1u)) >> 16);   // RNE
}

// ---------------- kernel 1: transpose + zero out + counter -------------------
// blocks [0,40):   ApT/AmT[k][o][d] = (Mp +/- Mm)[k][d][o]
// blocks [40,168): zero d_out (2 MiB); block 40 zeros the task counter
__global__ __launch_bounds__(256)
void k_pre(const float* __restrict__ Mp, const float* __restrict__ Mm,
           float* __restrict__ ApT, float* __restrict__ AmT,
           float* __restrict__ out, int* __restrict__ counter) {
    __shared__ float tp[64 * 65], tm[64 * 65];
    if (blockIdx.x < 40) {
        const int k = blockIdx.x, tid = threadIdx.x;
        for (int f = tid; f < 4096; f += 256) {          // f = d*64 + o
            int d = f >> 6, o = f & 63;
            float p = Mp[k * 4096 + f], m = Mm[k * 4096 + f];
            tp[o * 65 + d] = p + m;
            tm[o * 65 + d] = p - m;
        }
        __syncthreads();
        for (int f = tid; f < 4096; f += 256) {          // f = o*64 + d
            int o = f >> 6, d = f & 63;
            ApT[k * 4096 + f] = tp[o * 65 + d];
            AmT[k * 4096 + f] = tm[o * 65 + d];
        }
    } else {
        const int bz = blockIdx.x - 40;                  // 128 blocks x 4096 floats
        if (bz == 0 && threadIdx.x == 0) *counter = 0;
        float* po = out + bz * 4096;
        #pragma unroll
        for (int i = 0; i < 4; ++i)
            *(f32x4*)(po + (threadIdx.x + i * 256) * 4) = (f32x4){0.f, 0.f, 0.f, 0.f};
    }
}

// ---------------- kernel 2: xpad  ||  build W --------------------------------
// blocks [0,256):    xpad[b][r][d] bf16 (r<4096 zeros, 4096+t = x[b,t,:])
// blocks [256,2304): build Wtot[s][o][d]: one s-PARITY per block (32 s each)
__global__ __launch_bounds__(256)
void k_mid(const float* __restrict__ x, u16* __restrict__ xpad,
           const float* __restrict__ phi, const float* __restrict__ ApT,
           const float* __restrict__ AmT, const float* __restrict__ Mar,
           u16* __restrict__ wg) {
    if (blockIdx.x < 256) {
        const int u = blockIdx.x;
        #pragma unroll
        for (int i = 0; i < 4; ++i) {
            int gid = (u * 4 + i) * 256 + threadIdx.x;
            int b = gid >> 17, rem = gid & 131071;
            int r = rem >> 4, c4 = rem & 15;
            u16 o0 = 0, o1 = 0, o2 = 0, o3 = 0;
            if (r >= 4096) {
                const f32x4 v = *(const f32x4*)(x + ((b << 12) + (r - 4096)) * 64 + c4 * 4);
                o0 = f2bf(v.x); o1 = f2bf(v.y); o2 = f2bf(v.z); o3 = f2bf(v.w);
            }
            u16* p = xpad + ((b << 13) + r) * 64 + c4 * 4;
            p[0] = o0; p[1] = o1; p[2] = o2; p[3] = o3;
        }
    } else {
        const int bi  = blockIdx.x - 256;
        const int par = bi & 1;                          // s parity
        const int sbq = bi >> 1;
        const int sb  = sbq >> 4, qb = sbq & 15;
        const int q   = qb * 256 + threadIdx.x;
        const int o   = q >> 6, d = q & 63;
        const float* A = (par ? AmT : ApT);

        float a[40];
        #pragma unroll
        for (int k = 0; k < 40; ++k) a[k] = A[k * 4096 + q];   // coalesced

        #pragma unroll 2
        for (int m = 0; m < 32; ++m) {
            const int s = sb * 64 + 2 * m + par;
            const float* ph = phi + s * 40;              // wave-uniform -> s_load
            float e0 = 0.f, e1 = 0.f;
            #pragma unroll
            for (int k = 0; k < 40; k += 2) { e0 += ph[k] * a[k]; e1 += ph[k + 1] * a[k + 1]; }
            float ev = e0 + e1;
            if (s < 3) ev += Mar[o * 192 + d * 3 + s];   // fold AR term
            wg[(size_t)s * 4096 + q] = f2bf(ev);
        }
    }
}

// ---------------- kernel 3: conv-GEMM, B streamed from global ----------------
// A = x window in LDS (48 KB, 0-conflict swizzle). B = W[s] straight from
// L2-resident global (J-major order), register double-buffered one s ahead.
// ZERO barriers in the K-loop (only one after x staging). Waves=(par,batch),
// mt=8 x nt=4, J-major dynamic order + 32-s tail taper. LDS ops/j: 26 -> 16,
// MfmaUtil ceiling ~44% -> ~69%.
__global__ __launch_bounds__(256, 2)
void k_spectral(const u16* __restrict__ xpad, const u16* __restrict__ wg,
                float* __restrict__ out, int* __restrict__ counter) {
    __shared__ __align__(16) u16 xs[2 * 191 * 64];       // 47.75 KB x window
    __shared__ int sh;

    const int tid  = threadIdx.x;
    const int lane = tid & 63, w = tid >> 6;
    const int m15  = lane & 15, q4 = lane >> 4;
    const int par  = w >> 1, batch = w & 1;              // wave = (parity, batch)

    for (;;) {
        __syncthreads();                                 // xs/sh reuse guard
        if (tid == 0) sh = atomicAdd(counter, 1);
        __syncthreads();
        const int U = sh;
        if (U >= 1120) break;

        // taper: U<992 -> full unit; else half task (32-s) of unit 992+(U-992)/2
        int mu = U, shalf = 0, slen = 64;
        if (U >= 992) { mu = 992 + ((U - 992) >> 1); shalf = (U - 992) & 1; slen = 32; }
        // J-major unit decode: group g=J>>1, G(g)=g(65-g), column cnt=32-g
        int g = 0;
        #pragma unroll 1
        while (g < 31 && (g + 1) * (64 - g) <= mu) ++g;
        const int rem = mu - g * (65 - g);
        const int cnt = 32 - g;
        const int col = (rem >= cnt) ? 1 : 0;
        const int J = 2 * g + col;
        const int I = g + (col ? rem - cnt : rem);
        const int t0 = I << 7, s0 = (J << 6) + (shalf << 5);
        const int nrows = 127 + slen;
        const int jmax = slen >> 1;
        const int base = 4096 + t0 - s0 - (slen - 1);    // window start row in xpad

        // ---- stage x window: nrows rows/batch ----
        #pragma unroll
        for (int b = 0; b < 2; ++b) {
            #pragma unroll 1
            for (int f = tid; f < nrows * 8; f += 256) {
                int r = f >> 3, c = f & 7;
                bf16x8 v = *(const bf16x8*)(xpad + (size_t)((b << 13) + base + r) * 64 + c * 8);
                *(bf16x8*)(xs + ((b * 191 + r) * 8 + (c ^ (r & 7))) * 8) = v;
            }
        }

        f32x4 acc[8][4];
        #pragma unroll
        for (int mt = 0; mt < 8; ++mt)
            #pragma unroll
            for (int nt = 0; nt < 4; ++nt)
                acc[mt][nt] = (f32x4){0.f, 0.f, 0.f, 0.f};

        const u16* xb = xs + batch * (191 * 64);

        // B-frag base for this wave: W[s][o=nt*16+m15][d=kq*8..+8], kq=ks*4+q4
        const u16* wptr = wg + (size_t)(s0 + par) * 4096 + m15 * 64 + q4 * 8;

        auto computeS = [&](int ds, bf16x8 (&bc)[4][2]) {
            #pragma unroll
            for (int ks = 0; ks < 2; ++ks) {
                const int kq = ks * 4 + q4;
                #pragma unroll
                for (int mt = 0; mt < 8; ++mt) {
                    int r = mt * 16 + m15 + (slen - 1) - ds;   // in [0, nrows-1]
                    bf16x8 av = *(const bf16x8*)(xb + (r * 8 + (kq ^ (r & 7))) * 8);
                    #pragma unroll
                    for (int nt = 0; nt < 4; ++nt)
                        acc[mt][nt] = __builtin_amdgcn_mfma_f32_16x16x32_bf16(
                            av, bc[nt][ks], acc[mt][nt], 0, 0, 0);
                }
            }
        };

        // prefetch B for first s (s0 + par)
        bf16x8 bA[4][2], bB[4][2];
        #pragma unroll
        for (int nt = 0; nt < 4; ++nt) {
            bA[nt][0] = *(const bf16x8*)(wptr + nt * 1024);
            bA[nt][1] = *(const bf16x8*)(wptr + nt * 1024 + 32);
        }
        __syncthreads();                                 // xs visible to all waves

        #pragma unroll 1
        for (int jj = 0; jj < (jmax >> 1); ++jj) {
            const int ds0 = 4 * jj + par;
            {   // even j: prefetch s+2 into bB, compute with bA
                const u16* wn = wptr + 8192;
                #pragma unroll
                for (int nt = 0; nt < 4; ++nt) {
                    bB[nt][0] = *(const bf16x8*)(wn + nt * 1024);
                    bB[nt][1] = *(const bf16x8*)(wn + nt * 1024 + 32);
                }
                computeS(ds0, bA);
            }
            {   // odd j: prefetch s+4 into bA (guarded), compute with bB
                if (jj < (jmax >> 1) - 1) {
                    const u16* wn = wptr + 16384;
                    #pragma unroll
                    for (int nt = 0; nt < 4; ++nt) {
                        bA[nt][0] = *(const bf16x8*)(wn + nt * 1024);
                        bA[nt][1] = *(const bf16x8*)(wn + nt * 1024 + 32);
                    }
                }
                computeS(ds0 + 2, bB);
            }
            wptr += 16384;
        }

        // ---- merge parity-1 partials into parity-0 accs via LDS (xs dead) ----
        float* fs = (float*)xs;                          // 4096 floats (16 KB)
        #pragma unroll
        for (int rd = 0; rd < 4; ++rd) {
            __syncthreads();                             // rd=0: all K-loops done
            if (par == 1) {
                #pragma unroll
                for (int i = 0; i < 8; ++i) {
                    int ti = rd * 8 + i;
                    *(f32x4*)(fs + (batch * 8 + i) * 256 + lane * 4) = acc[ti >> 2][ti & 3];
                }
            }
            __syncthreads();
            if (par == 0) {
                #pragma unroll
                for (int i = 0; i < 8; ++i) {
                    int ti = rd * 8 + i;
                    f32x4 v = *(const f32x4*)(fs + (batch * 8 + i) * 256 + lane * 4);
                    acc[ti >> 2][ti & 3] += v;
                }
            }
        }

        // ---- epilogue (parity-0 waves only): coalesced fp32 atomics ----
        if (par == 0) {
            #pragma unroll
            for (int mt = 0; mt < 8; ++mt) {
                int t = t0 + mt * 16 + q4 * 4;
                #pragma unroll
                for (int nt = 0; nt < 4; ++nt) {
                    int o = nt * 16 + m15;
                    float* op = out + (size_t)((batch << 12) + t) * 64 + o;
                    #pragma unroll
                    for (int r = 0; r < 4; ++r)
                        atomicAdd(op + r * 64, acc[mt][nt][r]);
                }
            }
        }
    }
}

// ---------------------------------------------------------------------------
extern "C" void kernel_launch(void* const* d_in, const int* in_sizes, int n_in,
                              void* d_out, int out_size, void* d_ws, size_t ws_size,
                              hipStream_t stream) {
    const float* x   = (const float*)d_in[0];   // (2, 4096, 64)
    const float* phi = (const float*)d_in[1];   // (4096, 40)
    const float* M   = (const float*)d_in[2];   // (64, 64, 3)
    const float* Mp  = (const float*)d_in[3];   // (40, 64, 64)
    const float* Mm  = (const float*)d_in[4];   // (40, 64, 64)
    float* out = (float*)d_out;                 // (2, 4096, 64)

    // ws: [0,4096) counter | xpad 2 MiB | wg 32 MiB | ApT/AmT 2x640 KiB
    int* counter = (int*)d_ws;
    u16* xpad = (u16*)((char*)d_ws + 4096);
    u16* wg   = (u16*)((char*)d_ws + 4096 + 2097152);
    float* ApT = (float*)((char*)d_ws + 4096 + 2097152 + 33554432);
    float* AmT = ApT + 40 * 4096;

    k_pre<<<168, 256, 0, stream>>>(Mp, Mm, ApT, AmT, out, counter);
    k_mid<<<2304, 256, 0, stream>>>(x, xpad, phi, ApT, AmT, M, wg);
    k_spectral<<<512, 256, 0, stream>>>(xpad, wg, out, counter);
}